// Round 1
// baseline (910.524 us; speedup 1.0000x reference)
//
#include <hip/hip_runtime.h>
#include <hip/hip_bf16.h>

// Problem constants (fixed by setup_inputs)
#define N_INST 524288
#define NF     256
#define LDIM   128
#define NBAGS  4096

typedef __attribute__((ext_vector_type(8)))  short          short8;
typedef __attribute__((ext_vector_type(16))) float          f32x16;
typedef __attribute__((ext_vector_type(4)))  unsigned short ushort4v;
typedef __attribute__((ext_vector_type(4)))  int            int4v;

__device__ __forceinline__ unsigned short f2bf(float f) {
    unsigned u = __float_as_uint(f);
    unsigned r = u + 0x7FFFu + ((u >> 16) & 1u);   // round-to-nearest-even
    return (unsigned short)(r >> 16);
}

// ---------------------------------------------------------------------------
// Kernel 0: pack B̂ = [W_V | W_U] (column-interleaved per 32-col tile pair)
// into MFMA B-fragment order: Bws[ks(16)][ct(8)][lane(64)][j(8)] bf16.
// ct = cg*2 + vu ; n = (ct>>1)*32 + (lane&31) ; k = ks*16 + (lane>>5)*8 + j
// ---------------------------------------------------------------------------
__global__ __launch_bounds__(256) void k_build(const float* __restrict__ W_V,
                                               const float* __restrict__ W_U,
                                               unsigned short* __restrict__ Bws) {
    int idx  = blockIdx.x * 256 + threadIdx.x;       // 0..65535
    int j    = idx & 7;
    int lane = (idx >> 3) & 63;
    int ct   = (idx >> 9) & 7;
    int ks   = idx >> 12;
    int k    = ks * 16 + ((lane >> 5) << 3) + j;
    int n    = ((ct >> 1) << 5) + (lane & 31);
    const float* src = (ct & 1) ? W_U : W_V;
    Bws[idx] = f2bf(src[k * LDIM + n]);
}

// ---------------------------------------------------------------------------
// Kernel 1: exclusive prefix-scan of split_sizes -> offs[0..NBAGS]
// Robust to the sizes buffer being int64 or int32 (probe word 1: high word of
// sizes[0] is 0 for int64; sizes[1] >= 63 > 0 for int32).
// ---------------------------------------------------------------------------
__global__ __launch_bounds__(256) void k_scan(const int* __restrict__ sraw,
                                              int* __restrict__ offs) {
    __shared__ int csum[256];
    __shared__ int cpref[256];
    const int t = threadIdx.x;
    const bool is64 = (sraw[1] == 0);
    int local[16];
    int ssum = 0;
    for (int j = 0; j < 16; ++j) {
        int i = t * 16 + j;
        int v = is64 ? sraw[2 * i] : sraw[i];
        local[j] = v;
        ssum += v;
    }
    csum[t] = ssum;
    __syncthreads();
    if (t == 0) {
        int run = 0;
        for (int i = 0; i < 256; ++i) { cpref[i] = run; run += csum[i]; }
    }
    __syncthreads();
    int run = cpref[t];
    for (int j = 0; j < 16; ++j) { offs[t * 16 + j] = run; run += local[j]; }
    if (t == 255) offs[NBAGS] = run;
}

// ---------------------------------------------------------------------------
// Kernel 2: the fused GEMM. Per 64-row block:
//   v,u = feats @ [W_V|W_U]  (bf16 MFMA 32x32x16, K=256 in 16 steps)
//   scores = sum_n tanh(v+bV)*sig(u+bU)*w_att  (in-register per wave pair)
//   inst_pred = feats @ W_ins + b_ins  (exact fp32, from staged loads)
// 4 waves; wave cg owns col-tile pair (V,U) for n in [cg*32, cg*32+32).
// ---------------------------------------------------------------------------
__global__ __launch_bounds__(256, 3) void k_gemm(
    const float* __restrict__ feats, const unsigned short* __restrict__ Bws,
    const float* __restrict__ W_ins, const float* __restrict__ b_ins,
    const float* __restrict__ b_V,   const float* __restrict__ b_U,
    const float* __restrict__ w_att, const float* __restrict__ b_att,
    float* __restrict__ scores, float* __restrict__ inst_out) {

    __shared__ unsigned short Al[1024];   // A frags: [rt(2)][lane(64)][8 halves]
    __shared__ unsigned short Bl[4096];   // B frags: [ct(8)][lane(64)][8 halves]
    __shared__ float winsl[NF];
    __shared__ float bVl[LDIM], bUl[LDIM], wal[LDIM];
    __shared__ float Sp[64][4];

    const int t    = threadIdx.x;
    const int lane = t & 63;
    const int cg   = t >> 6;          // wave id == col group (0..3)
    const int row  = t >> 2;          // staging row within block (0..63)
    const int seg  = t & 3;           // staging k-quarter (4 floats each)
    const long r0  = (long)blockIdx.x * 64;

    winsl[t] = W_ins[t];
    if (t < LDIM) { bVl[t] = b_V[t]; bUl[t] = b_U[t]; wal[t] = w_att[t]; }

    f32x16 acc[2][2] = {};            // [row-tile rt][vu]
    float pacc = 0.f;

    const float* arow = feats + (r0 + row) * NF + seg * 4;
    const int4v* bsrc = (const int4v*)Bws;
    // A staging address: klocal = seg*4+j -> quad = seg>>1, pos = (seg&1)*4
    const int aoff = (((row >> 5) * 64) + ((seg >> 1) * 32) + (row & 31)) * 8
                     + (seg & 1) * 4;

    for (int ks = 0; ks < 16; ++ks) {
        __syncthreads();                       // prev frag reads done
        float4 av = *(const float4*)(arow + ks * 16);
        float4 wv = *(const float4*)&winsl[ks * 16 + seg * 4];
        pacc += av.x * wv.x + av.y * wv.y + av.z * wv.z + av.w * wv.w;
        ushort4v a4;
        a4.x = f2bf(av.x); a4.y = f2bf(av.y); a4.z = f2bf(av.z); a4.w = f2bf(av.w);
        *(ushort4v*)&Al[aoff] = a4;
        ((int4v*)Bl)[t]       = bsrc[ks * 512 + t];
        ((int4v*)Bl)[t + 256] = bsrc[ks * 512 + t + 256];
        __syncthreads();

        short8 a0 = *(const short8*)&Al[(0 * 64 + lane) * 8];
        short8 a1 = *(const short8*)&Al[(1 * 64 + lane) * 8];
        short8 bv = *(const short8*)&Bl[((cg * 2 + 0) * 64 + lane) * 8];
        short8 bu = *(const short8*)&Bl[((cg * 2 + 1) * 64 + lane) * 8];
        acc[0][0] = __builtin_amdgcn_mfma_f32_32x32x16_bf16(a0, bv, acc[0][0], 0, 0, 0);
        acc[0][1] = __builtin_amdgcn_mfma_f32_32x32x16_bf16(a0, bu, acc[0][1], 0, 0, 0);
        acc[1][0] = __builtin_amdgcn_mfma_f32_32x32x16_bf16(a1, bv, acc[1][0], 0, 0, 0);
        acc[1][1] = __builtin_amdgcn_mfma_f32_32x32x16_bf16(a1, bu, acc[1][1], 0, 0, 0);
    }

    // ---- epilogue: gated-attention score partials -------------------------
    // C/D layout (verified): col = lane&31, row = (reg&3) + 8*(reg>>2) + 4*(lane>>5)
    const int   c32 = lane & 31;
    const int   n   = cg * 32 + c32;
    const float bv0 = bVl[n], bu0 = bUl[n], wn = wal[n];
    const int   rh  = lane >> 5;
    #pragma unroll
    for (int rt = 0; rt < 2; ++rt) {
        float s[16];
        #pragma unroll
        for (int r = 0; r < 16; ++r) {
            float v  = acc[rt][0][r] + bv0;
            float u  = acc[rt][1][r] + bu0;
            float ev = __expf(2.f * v);
            float th = 1.f - 2.f * __builtin_amdgcn_rcpf(ev + 1.f);   // tanh(v)
            float sg = __builtin_amdgcn_rcpf(1.f + __expf(-u));       // sigmoid(u)
            s[r] = th * sg * wn;
        }
        #pragma unroll
        for (int r = 0; r < 16; ++r) {                  // reduce over 32 cols
            float x = s[r];
            x += __shfl_xor(x, 1);
            x += __shfl_xor(x, 2);
            x += __shfl_xor(x, 4);
            x += __shfl_xor(x, 8);
            x += __shfl_xor(x, 16);
            s[r] = x;
        }
        if (c32 == 0) {
            #pragma unroll
            for (int r = 0; r < 16; ++r) {
                int rl = (r & 3) + 8 * (r >> 2) + 4 * rh;
                Sp[rt * 32 + rl][cg] = s[r];
            }
        }
    }

    // ---- inst_pred (exact fp32): combine the 4 k-quarter partials ---------
    float pt = pacc;
    pt += __shfl_xor(pt, 1);
    pt += __shfl_xor(pt, 2);
    if (seg == 0) inst_out[r0 + row] = pt + b_ins[0];

    __syncthreads();
    if (t < 64)
        scores[r0 + t] = Sp[t][0] + Sp[t][1] + Sp[t][2] + Sp[t][3] + b_att[0];
}

// ---------------------------------------------------------------------------
// Kernel 3: per-bag softmax + weighted sum. One wave per bag.
// ---------------------------------------------------------------------------
__global__ __launch_bounds__(64) void k_bags(const int* __restrict__ offs,
                                             const float* __restrict__ scores,
                                             const float* __restrict__ inst,
                                             float* __restrict__ bag_out) {
    const int b    = blockIdx.x;
    const int lane = threadIdx.x;
    const int s0 = offs[b], s1 = offs[b + 1];
    float m = -1e30f;
    for (int i = s0 + lane; i < s1; i += 64) m = fmaxf(m, scores[i]);
    #pragma unroll
    for (int d = 32; d; d >>= 1) m = fmaxf(m, __shfl_xor(m, d));
    float se = 0.f, sp = 0.f;
    for (int i = s0 + lane; i < s1; i += 64) {
        float e = __expf(scores[i] - m);
        se += e;
        sp += e * inst[i];
    }
    #pragma unroll
    for (int d = 32; d; d >>= 1) { se += __shfl_xor(se, d); sp += __shfl_xor(sp, d); }
    if (lane == 0) bag_out[b] = sp / se;
}

// ---------------------------------------------------------------------------
extern "C" void kernel_launch(void* const* d_in, const int* in_sizes, int n_in,
                              void* d_out, int out_size, void* d_ws, size_t ws_size,
                              hipStream_t stream) {
    const float* feats  = (const float*)d_in[0];
    const int*   sizesr = (const int*)d_in[1];   // int64 or int32, probed in-kernel
    const float* W_ins  = (const float*)d_in[2];
    const float* b_ins  = (const float*)d_in[3];
    const float* W_V    = (const float*)d_in[4];
    const float* b_V    = (const float*)d_in[5];
    const float* W_U    = (const float*)d_in[6];
    const float* b_U    = (const float*)d_in[7];
    const float* w_att  = (const float*)d_in[8];
    const float* b_att  = (const float*)d_in[9];

    // ws layout: [0,128K) Bws bf16 | [128K,~144K) offs | [160K, 160K+2M) scores
    unsigned short* Bws    = (unsigned short*)d_ws;
    int*            offs   = (int*)((char*)d_ws + (128 << 10));
    float*          scores = (float*)((char*)d_ws + (160 << 10));

    float* bag_out  = (float*)d_out;
    float* inst_out = (float*)d_out + NBAGS;

    hipLaunchKernelGGL(k_build, dim3(256), dim3(256), 0, stream, W_V, W_U, Bws);
    hipLaunchKernelGGL(k_scan,  dim3(1),   dim3(256), 0, stream, sizesr, offs);
    hipLaunchKernelGGL(k_gemm,  dim3(N_INST / 64), dim3(256), 0, stream,
                       feats, Bws, W_ins, b_ins, b_V, b_U, w_att, b_att,
                       scores, inst_out);
    hipLaunchKernelGGL(k_bags,  dim3(NBAGS), dim3(64), 0, stream,
                       offs, scores, inst_out, bag_out);
}

// Round 2
// 887.250 us; speedup vs baseline: 1.0262x; 1.0262x over previous
//
#include <hip/hip_runtime.h>
#include <hip/hip_bf16.h>

// Problem constants (fixed by setup_inputs)
#define N_INST 524288
#define NF     256
#define LDIM   128
#define NBAGS  4096
#define BM     128     // rows per block

typedef __attribute__((ext_vector_type(8)))  short          short8;
typedef __attribute__((ext_vector_type(16))) float          f32x16;
typedef __attribute__((ext_vector_type(4)))  unsigned short ushort4v;
typedef __attribute__((ext_vector_type(4)))  int            int4v;

__device__ __forceinline__ unsigned short f2bf(float f) {
    unsigned u = __float_as_uint(f);
    unsigned r = u + 0x7FFFu + ((u >> 16) & 1u);   // round-to-nearest-even
    return (unsigned short)(r >> 16);
}

// ---------------------------------------------------------------------------
// Kernel 0: pack B̂ = [W_V | W_U] into MFMA B-fragment order:
// Bws[ks(16)][ct(8)][lane(64)][j(8)] bf16.
// ct = cg*2 + vu ; n = (ct>>1)*32 + (lane&31) ; k = ks*16 + (lane>>5)*8 + j
// ---------------------------------------------------------------------------
__global__ __launch_bounds__(256) void k_build(const float* __restrict__ W_V,
                                               const float* __restrict__ W_U,
                                               unsigned short* __restrict__ Bws) {
    int idx  = blockIdx.x * 256 + threadIdx.x;       // 0..65535
    int j    = idx & 7;
    int lane = (idx >> 3) & 63;
    int ct   = (idx >> 9) & 7;
    int ks   = idx >> 12;
    int k    = ks * 16 + ((lane >> 5) << 3) + j;
    int n    = ((ct >> 1) << 5) + (lane & 31);
    const float* src = (ct & 1) ? W_U : W_V;
    Bws[idx] = f2bf(src[k * LDIM + n]);
}

// ---------------------------------------------------------------------------
// Kernel 1: exclusive prefix-scan of split_sizes -> offs[0..NBAGS]
// ---------------------------------------------------------------------------
__global__ __launch_bounds__(256) void k_scan(const int* __restrict__ sraw,
                                              int* __restrict__ offs) {
    __shared__ int csum[256];
    __shared__ int cpref[256];
    const int t = threadIdx.x;
    const bool is64 = (sraw[1] == 0);
    int local[16];
    int ssum = 0;
    for (int j = 0; j < 16; ++j) {
        int i = t * 16 + j;
        int v = is64 ? sraw[2 * i] : sraw[i];
        local[j] = v;
        ssum += v;
    }
    csum[t] = ssum;
    __syncthreads();
    if (t == 0) {
        int run = 0;
        for (int i = 0; i < 256; ++i) { cpref[i] = run; run += csum[i]; }
    }
    __syncthreads();
    int run = cpref[t];
    for (int j = 0; j < 16; ++j) { offs[t * 16 + j] = run; run += local[j]; }
    if (t == 255) offs[NBAGS] = run;
}

// ---------------------------------------------------------------------------
// Kernel 2: fused GEMM, BM=128 rows/block, BN=256 (V128|U128), BK=16, 16 iters.
// Depth-2 register prefetch (A from HBM, B from L2) + double-buffered LDS,
// ONE barrier per K-iter. Named f32x16 accumulators (no arrays -> no scratch).
// ---------------------------------------------------------------------------
__global__ __launch_bounds__(256, 2) void k_gemm(
    const float* __restrict__ feats, const unsigned short* __restrict__ Bws,
    const float* __restrict__ W_ins, const float* __restrict__ b_ins,
    const float* __restrict__ b_V,   const float* __restrict__ b_U,
    const float* __restrict__ w_att, const float* __restrict__ b_att,
    float* __restrict__ scores, float* __restrict__ inst_out) {

    __shared__ unsigned short Al[2][2048];   // [buf][rt(4)][khalf(2)][row32][8]
    __shared__ unsigned short Bl[2][4096];   // [buf][ct(8)][lane(64)][8]
    __shared__ float winsl[NF];
    __shared__ float bVl[LDIM], bUl[LDIM], wal[LDIM];
    __shared__ float Sp[BM][4];

    const int t    = threadIdx.x;
    const int lane = t & 63;
    const int cg   = t >> 6;              // wave id == col group (0..3)
    const long r0  = (long)blockIdx.x * BM;

    // staging: slot0 = rows 0..63, slot1 = rows 64..127; 4 k-quarters/row
    const int row0 = t >> 2;
    const int q    = t & 3;
    const int row1 = row0 + 64;

    winsl[t] = W_ins[t];
    if (t < LDIM) { bVl[t] = b_V[t]; bUl[t] = b_U[t]; wal[t] = w_att[t]; }

    const float* arow0 = feats + (r0 + row0) * NF + q * 4;
    const float* arow1 = feats + (r0 + row1) * NF + q * 4;
    const int4v* bsrc  = (const int4v*)Bws;

    const int aoff0 = ((row0 >> 5) * 64 + (q >> 1) * 32 + (row0 & 31)) * 8 + (q & 1) * 4;
    const int aoff1 = ((row1 >> 5) * 64 + (q >> 1) * 32 + (row1 & 31)) * 8 + (q & 1) * 4;

    // ---- depth-2 prefetch prologue (issued before the preamble barrier) ----
    float4 pa0_0 = *(const float4*)(arow0);
    float4 pa1_0 = *(const float4*)(arow1);
    int4v  pb0_0 = bsrc[t];
    int4v  pb1_0 = bsrc[t + 256];
    float4 pa0_1 = *(const float4*)(arow0 + 16);
    float4 pa1_1 = *(const float4*)(arow1 + 16);
    int4v  pb0_1 = bsrc[512 + t];
    int4v  pb1_1 = bsrc[512 + t + 256];

    f32x16 accV0 = {}, accV1 = {}, accV2 = {}, accV3 = {};
    f32x16 accU0 = {}, accU1 = {}, accU2 = {}, accU3 = {};
    float pacc0 = 0.f, pacc1 = 0.f;

    __syncthreads();   // winsl/bias visible

    #pragma unroll
    for (int ks = 0; ks < 16; ++ks) {
        // select prefetch register set (compile-time after full unroll)
        float4 av0 = (ks & 1) ? pa0_1 : pa0_0;
        float4 av1 = (ks & 1) ? pa1_1 : pa1_0;
        int4v  bv0 = (ks & 1) ? pb0_1 : pb0_0;
        int4v  bv1 = (ks & 1) ? pb1_1 : pb1_0;
        const int X = ks & 1;

        // instance-head fp32 dot on the staged quarters
        float4 wv = *(const float4*)&winsl[ks * 16 + q * 4];
        pacc0 += av0.x * wv.x + av0.y * wv.y + av0.z * wv.z + av0.w * wv.w;
        pacc1 += av1.x * wv.x + av1.y * wv.y + av1.z * wv.z + av1.w * wv.w;

        // convert + stage into LDS buffer X
        ushort4v c0, c1;
        c0.x = f2bf(av0.x); c0.y = f2bf(av0.y); c0.z = f2bf(av0.z); c0.w = f2bf(av0.w);
        c1.x = f2bf(av1.x); c1.y = f2bf(av1.y); c1.z = f2bf(av1.z); c1.w = f2bf(av1.w);
        *(ushort4v*)&Al[X][aoff0] = c0;
        *(ushort4v*)&Al[X][aoff1] = c1;
        ((int4v*)Bl[X])[t]       = bv0;
        ((int4v*)Bl[X])[t + 256] = bv1;

        // issue loads for ks+2 into the just-freed register set
        if (ks < 14) {
            if (X == 0) {
                pa0_0 = *(const float4*)(arow0 + (ks + 2) * 16);
                pa1_0 = *(const float4*)(arow1 + (ks + 2) * 16);
                pb0_0 = bsrc[(ks + 2) * 512 + t];
                pb1_0 = bsrc[(ks + 2) * 512 + t + 256];
            } else {
                pa0_1 = *(const float4*)(arow0 + (ks + 2) * 16);
                pa1_1 = *(const float4*)(arow1 + (ks + 2) * 16);
                pb0_1 = bsrc[(ks + 2) * 512 + t];
                pb1_1 = bsrc[(ks + 2) * 512 + t + 256];
            }
        }

        __syncthreads();   // buffer X fully staged

        short8 fa0 = *(const short8*)&Al[X][(0 * 64 + lane) * 8];
        short8 fa1 = *(const short8*)&Al[X][(1 * 64 + lane) * 8];
        short8 fa2 = *(const short8*)&Al[X][(2 * 64 + lane) * 8];
        short8 fa3 = *(const short8*)&Al[X][(3 * 64 + lane) * 8];
        short8 fbv = *(const short8*)&Bl[X][((cg * 2 + 0) * 64 + lane) * 8];
        short8 fbu = *(const short8*)&Bl[X][((cg * 2 + 1) * 64 + lane) * 8];
        accV0 = __builtin_amdgcn_mfma_f32_32x32x16_bf16(fa0, fbv, accV0, 0, 0, 0);
        accU0 = __builtin_amdgcn_mfma_f32_32x32x16_bf16(fa0, fbu, accU0, 0, 0, 0);
        accV1 = __builtin_amdgcn_mfma_f32_32x32x16_bf16(fa1, fbv, accV1, 0, 0, 0);
        accU1 = __builtin_amdgcn_mfma_f32_32x32x16_bf16(fa1, fbu, accU1, 0, 0, 0);
        accV2 = __builtin_amdgcn_mfma_f32_32x32x16_bf16(fa2, fbv, accV2, 0, 0, 0);
        accU2 = __builtin_amdgcn_mfma_f32_32x32x16_bf16(fa2, fbu, accU2, 0, 0, 0);
        accV3 = __builtin_amdgcn_mfma_f32_32x32x16_bf16(fa3, fbv, accV3, 0, 0, 0);
        accU3 = __builtin_amdgcn_mfma_f32_32x32x16_bf16(fa3, fbu, accU3, 0, 0, 0);
    }

    // ---- epilogue: gated-attention scores ---------------------------------
    // C/D layout: col = lane&31, row = (reg&3) + 8*(reg>>2) + 4*(lane>>5)
    const int   c32 = lane & 31;
    const int   nn  = cg * 32 + c32;
    const float bv0s = bVl[nn], bu0s = bUl[nn], wn = wal[nn];
    const int   rh  = lane >> 5;

#define EPILOG(RT, AV, AU)                                                    \
    {                                                                         \
        _Pragma("unroll")                                                     \
        for (int r = 0; r < 16; ++r) {                                        \
            float v  = AV[r] + bv0s;                                          \
            float u  = AU[r] + bu0s;                                          \
            float ev = __expf(2.f * v);                                       \
            float th = 1.f - 2.f * __builtin_amdgcn_rcpf(ev + 1.f);           \
            float sg = __builtin_amdgcn_rcpf(1.f + __expf(-u));               \
            float x  = th * sg * wn;                                          \
            x += __shfl_xor(x, 1);                                            \
            x += __shfl_xor(x, 2);                                            \
            x += __shfl_xor(x, 4);                                            \
            x += __shfl_xor(x, 8);                                            \
            x += __shfl_xor(x, 16);                                           \
            if (c32 == 0)                                                     \
                Sp[RT * 32 + (r & 3) + 8 * (r >> 2) + 4 * rh][cg] = x;        \
        }                                                                     \
    }
    EPILOG(0, accV0, accU0)
    EPILOG(1, accV1, accU1)
    EPILOG(2, accV2, accU2)
    EPILOG(3, accV3, accU3)
#undef EPILOG

    // ---- inst_pred (exact fp32): combine 4 quarter-partials per row -------
    float pt0 = pacc0;
    pt0 += __shfl_xor(pt0, 1);
    pt0 += __shfl_xor(pt0, 2);
    float pt1 = pacc1;
    pt1 += __shfl_xor(pt1, 1);
    pt1 += __shfl_xor(pt1, 2);
    if (q == 0) {
        float bi = b_ins[0];
        inst_out[r0 + row0] = pt0 + bi;
        inst_out[r0 + row1] = pt1 + bi;
    }

    __syncthreads();
    if (t < BM)
        scores[r0 + t] = Sp[t][0] + Sp[t][1] + Sp[t][2] + Sp[t][3] + b_att[0];
}

// ---------------------------------------------------------------------------
// Kernel 3: per-bag softmax + weighted sum. One wave per bag.
// ---------------------------------------------------------------------------
__global__ __launch_bounds__(64) void k_bags(const int* __restrict__ offs,
                                             const float* __restrict__ scores,
                                             const float* __restrict__ inst,
                                             float* __restrict__ bag_out) {
    const int b    = blockIdx.x;
    const int lane = threadIdx.x;
    const int s0 = offs[b], s1 = offs[b + 1];
    float m = -1e30f;
    for (int i = s0 + lane; i < s1; i += 64) m = fmaxf(m, scores[i]);
    #pragma unroll
    for (int d = 32; d; d >>= 1) m = fmaxf(m, __shfl_xor(m, d));
    float se = 0.f, sp = 0.f;
    for (int i = s0 + lane; i < s1; i += 64) {
        float e = __expf(scores[i] - m);
        se += e;
        sp += e * inst[i];
    }
    #pragma unroll
    for (int d = 32; d; d >>= 1) { se += __shfl_xor(se, d); sp += __shfl_xor(sp, d); }
    if (lane == 0) bag_out[b] = sp / se;
}

// ---------------------------------------------------------------------------
extern "C" void kernel_launch(void* const* d_in, const int* in_sizes, int n_in,
                              void* d_out, int out_size, void* d_ws, size_t ws_size,
                              hipStream_t stream) {
    const float* feats  = (const float*)d_in[0];
    const int*   sizesr = (const int*)d_in[1];   // int64 or int32, probed in-kernel
    const float* W_ins  = (const float*)d_in[2];
    const float* b_ins  = (const float*)d_in[3];
    const float* W_V    = (const float*)d_in[4];
    const float* b_V    = (const float*)d_in[5];
    const float* W_U    = (const float*)d_in[6];
    const float* b_U    = (const float*)d_in[7];
    const float* w_att  = (const float*)d_in[8];
    const float* b_att  = (const float*)d_in[9];

    // ws layout: [0,128K) Bws bf16 | [128K,+16K) offs | [160K, 160K+2M) scores
    unsigned short* Bws    = (unsigned short*)d_ws;
    int*            offs   = (int*)((char*)d_ws + (128 << 10));
    float*          scores = (float*)((char*)d_ws + (160 << 10));

    float* bag_out  = (float*)d_out;
    float* inst_out = (float*)d_out + NBAGS;

    hipLaunchKernelGGL(k_build, dim3(256), dim3(256), 0, stream, W_V, W_U, Bws);
    hipLaunchKernelGGL(k_scan,  dim3(1),   dim3(256), 0, stream, sizesr, offs);
    hipLaunchKernelGGL(k_gemm,  dim3(N_INST / BM), dim3(256), 0, stream,
                       feats, Bws, W_ins, b_ins, b_V, b_U, w_att, b_att,
                       scores, inst_out);
    hipLaunchKernelGGL(k_bags,  dim3(NBAGS), dim3(64), 0, stream,
                       offs, scores, inst_out, bag_out);
}